// Round 1
// baseline (114.961 us; speedup 1.0000x reference)
//
#include <hip/hip_runtime.h>
#include <math.h>

#define NDIR 32
#define NH   256
#define BLK  512    // 8 waves/block
#define NB   1024   // 4 blocks/CU resident (LDS-capped)
#define PACKB 256   // prep grid (one max-slot per block)
#define UNIT 128    // items per work unit (2 x 64 lanes)
#define NSHARD 8    // work-steal counter shards (blockIdx&7 ~= XCD under round-robin)
#define WPS  ((NB * 8) / NSHARD)   // waves per shard = 1024 (static seed count)
#define SCALE    2048.0f
#define INVSCALE (1.0 / 2048.0)
#define BIAS  128.5f   // 127.5 (ref bias) + 1.0 (ceil folded into trunc)

// unit costs (relative VALU weight ~1 : 1.5 : 2)
#define CV 64
#define CE 96
#define CT 128

// ws layout in 4-byte words:
//  [8 .. 104)    : normalized dirs, 32 x 3 floats
//  [128 .. 384)  : per-block max(norm^2) slots (PACKB floats)
//  [384 .. 512)  : NSHARD work-steal counters, 16-word (64B) stride
//  [512 .. 512+2*K0) : packed f16 vertex table (uint2 per vertex), packed path only
//  [part_off ..)     : P partial int histograms, each 32*256 int32
#define WS_DIRS 8
#define WS_BMAX 128
#define WS_CTR  384
#define WS_TAB  512

typedef _Float16 half2v __attribute__((ext_vector_type(2)));

__device__ __forceinline__ unsigned rfl_u(unsigned x) { return __builtin_amdgcn_readfirstlane(x); }

__device__ __forceinline__ unsigned pack2(float x, float y) {
    union { half2v h; unsigned u; } c;
    c.h = half2v{(_Float16)x, (_Float16)y};   // RNE (v_cvt_f16_f32)
    return c.u;
}
__device__ __forceinline__ half2v upk(unsigned u) {
    union { unsigned u; half2v h; } c; c.u = u; return c.h;
}
__device__ __forceinline__ float hdot(half2v a, half2v b, float acc) {
#if __has_builtin(__builtin_amdgcn_fdot2)
    return __builtin_amdgcn_fdot2(a, b, acc, false);
#else
    return acc + (float)a.x * (float)b.x + (float)a.y * (float)b.y;
#endif
}
// bin = clip(trunc(hs), 0, 255); hs carries BIAS -> max+min + v_cvt_i32_f32
__device__ __forceinline__ int bin_of(float hs) {
    return (int)fminf(fmaxf(hs, 0.0f), 255.0f);
}

// monotone cost -> unit index (ceil), exact partition across shards
__device__ __forceinline__ int cost_to_unit(long long cost, int N0, int N1,
                                            long long C0, long long C1) {
    if (cost <= C0) return (int)((cost + (CV - 1)) / CV);
    cost -= C0;
    if (cost <= C1) return N0 + (int)((cost + (CE - 1)) / CE);
    cost -= C1;
    return N0 + N1 + (int)((cost + (CT - 1)) / CT);
}

// prep: zero partials + init steal counters + normalize dirs + pack f16 table
//       + per-block max slot (no atomics)
template <bool PACKED>
__global__ void __launch_bounds__(512) wect_prep_kernel(
    const float* __restrict__ dirs, const float* __restrict__ vc, int K0,
    int N0, int N1, long long C0, long long C1, long long Ctot,
    int P, int part_off, float* __restrict__ ws)
{
    int tid  = blockIdx.x * blockDim.x + threadIdx.x;
    int nthr = gridDim.x * blockDim.x;
    for (int i = tid; i < P * NDIR * NH; i += nthr)
        ((int*)ws)[part_off + i] = 0;
    if (blockIdx.x == 0 && threadIdx.x < NSHARD) {
        // shard s statically seeds units [Us, Us+WPS); counter starts at Us+WPS
        long long cs = (long long)threadIdx.x * Ctot / NSHARD;
        ((int*)ws)[WS_CTR + threadIdx.x * 16] =
            cost_to_unit(cs, N0, N1, C0, C1) + WPS;
    }
    if (blockIdx.x == 0 && threadIdx.x >= 64 && threadIdx.x < 64 + NDIR) {
        int d = threadIdx.x - 64;
        float x = dirs[d * 3 + 0], y = dirs[d * 3 + 1], z = dirs[d * 3 + 2];
        float n = fmaxf(sqrtf(x * x + y * y + z * z), 1e-12f);
        ws[WS_DIRS + d * 3 + 0] = x / n;
        ws[WS_DIRS + d * 3 + 1] = y / n;
        ws[WS_DIRS + d * 3 + 2] = z / n;
    }
    float m = 0.0f;
    uint2* tab = (uint2*)(ws + WS_TAB);
    for (int i = tid; i < K0; i += nthr) {
        float x = vc[3 * i + 0], y = vc[3 * i + 1], z = vc[3 * i + 2];
        m = fmaxf(m, x * x + y * y + z * z);
        if (PACKED) tab[i] = make_uint2(pack2(x, y), pack2(z, 0.0f));
    }
    __shared__ float wm[8];
    #pragma unroll
    for (int off = 32; off > 0; off >>= 1)
        m = fmaxf(m, __shfl_down(m, off, 64));
    if ((threadIdx.x & 63) == 0) wm[threadIdx.x >> 6] = m;
    __syncthreads();
    if (threadIdx.x == 0) {
        float r = wm[0];
        #pragma unroll
        for (int i = 1; i < 8; ++i) r = fmaxf(r, wm[i]);
        ws[WS_BMAX + blockIdx.x] = r;
    }
}

template <bool PACKED>
__global__ void __launch_bounds__(BLK, 8) wect_hist_kernel(
    const float* __restrict__ vc, const float* __restrict__ vw,
    const int*   __restrict__ ev, const float* __restrict__ ew,
    const int*   __restrict__ tv, const float* __restrict__ tw,
    int K0, int K1, int K2, int N0, int N1, int N2,
    long long C0, long long C1, long long Ctot,
    int P, int part_off, float* __restrict__ ws)
{
    __shared__ int hist[NDIR * NH];   // 32 KB -> 4 blocks/CU (512 thr) = 32 waves/CU
    for (int i = threadIdx.x; i < NDIR * NH; i += BLK) hist[i] = 0;

    const int wave = threadIdx.x >> 6;
    const int lane = threadIdx.x & 63;

    // reduce per-block max slots (wave-local, no atomics)
    float m = 0.0f;
    for (int i = lane; i < PACKB; i += 64) m = fmaxf(m, ws[WS_BMAX + i]);
    #pragma unroll
    for (int off = 32; off > 0; off >>= 1)
        m = fmaxf(m, __shfl_xor(m, off, 64));
    float maxh = fmaxf(sqrtf(m), 1e-12f);
    float inv  = 127.5f / maxh;

    // all 32 dirs per wave, packed f16 pairs pinned in SGPRs (64 SGPRs)
    unsigned sdxy[NDIR], sdz[NDIR];
    #pragma unroll
    for (int d = 0; d < NDIR; ++d) {
        float dx = ws[WS_DIRS + 3 * d + 0] * inv;
        float dy = ws[WS_DIRS + 3 * d + 1] * inv;
        float dz = ws[WS_DIRS + 3 * d + 2] * inv;
        sdxy[d] = rfl_u(pack2(dx, dy));
        sdz[d]  = rfl_u(pack2(dz, 0.0f));
    }
    __syncthreads();

    const uint2* tab = (const uint2*)(ws + WS_TAB);
    #define LDC(J, CXY, CZ)                                                  \
        do {                                                                 \
            if constexpr (PACKED) {                                          \
                uint2 r = tab[J];                                            \
                CXY = upk(r.x); CZ = upk(r.y);                               \
            } else {                                                         \
                float _x = vc[3 * (J) + 0], _y = vc[3 * (J) + 1], _z = vc[3 * (J) + 2]; \
                CXY = half2v{(_Float16)_x, (_Float16)_y};                    \
                CZ  = half2v{(_Float16)_z, (_Float16)0.0f};                  \
            }                                                                \
        } while (0)

    // ---- dynamic work stealing over units, sharded counters ----
    // shard = blockIdx&7 (~XCD under round-robin dispatch -> L2-local counter).
    // Each wave seeds one static unit, then steals; next-grab is prefetched so
    // the atomic's latency hides under the current unit's compute.
    const int shard = blockIdx.x & (NSHARD - 1);
    const int Us = cost_to_unit((long long)shard * Ctot / NSHARD, N0, N1, C0, C1);
    const int Ue = cost_to_unit((long long)(shard + 1) * Ctot / NSHARD, N0, N1, C0, C1);
    int* ctr = (int*)ws + WS_CTR + shard * 16;
    int cur = Us + ((blockIdx.x >> 3) << 3) + wave;   // wsid in [0, WPS)

    while (cur < Ue) {
        int nxt = 0;
        if (lane == 0) nxt = atomicAdd(ctr, 1);   // prefetch next unit id
        const int u = cur;

        if (u < N0) {
            // ---- vertex unit: sign +1 ----
            int base = u * UNIT;
            half2v xy[2], z[2]; int w[2];
            #pragma unroll
            for (int k = 0; k < 2; ++k) {
                int i = base + k * 64 + lane;
                int j = (i < K0) ? i : 0;
                LDC(j, xy[k], z[k]);
                w[k] = (i < K0) ? __float2int_rn(vw[j] * SCALE) : 0;
            }
            #pragma unroll
            for (int d = 0; d < NDIR; ++d) {
                half2v dxy = upk(sdxy[d]), dz = upk(sdz[d]);
                #pragma unroll
                for (int k = 0; k < 2; ++k) {
                    float h = hdot(xy[k], dxy, hdot(z[k], dz, BIAS));
                    atomicAdd(&hist[d * NH + bin_of(h)], w[k]);
                }
            }
        } else if (u < N0 + N1) {
            // ---- edge unit: sign -1 ----
            int base = (u - N0) * UNIT;
            half2v axy[2], az[2], bxy[2], bz[2]; int w[2];
            #pragma unroll
            for (int k = 0; k < 2; ++k) {
                int i = base + k * 64 + lane;
                int j = (i < K1) ? i : 0;
                int2 e = ((const int2*)ev)[j];
                LDC(e.x, axy[k], az[k]);
                LDC(e.y, bxy[k], bz[k]);
                w[k] = (i < K1) ? -__float2int_rn(ew[j] * SCALE) : 0;
            }
            #pragma unroll
            for (int d = 0; d < NDIR; ++d) {
                half2v dxy = upk(sdxy[d]), dz = upk(sdz[d]);
                #pragma unroll
                for (int k = 0; k < 2; ++k) {
                    float h = fmaxf(hdot(axy[k], dxy, hdot(az[k], dz, BIAS)),
                                    hdot(bxy[k], dxy, hdot(bz[k], dz, BIAS)));
                    atomicAdd(&hist[d * NH + bin_of(h)], w[k]);
                }
            }
        } else {
            // ---- triangle unit: sign +1 ----
            int base = (u - N0 - N1) * UNIT;
            half2v axy[2], az[2], bxy[2], bz[2], cxy[2], cz[2]; int w[2];
            #pragma unroll
            for (int k = 0; k < 2; ++k) {
                int i = base + k * 64 + lane;
                int j = (i < K2) ? i : 0;
                int va = tv[3 * j + 0], vb = tv[3 * j + 1], vcc = tv[3 * j + 2];
                LDC(va,  axy[k], az[k]);
                LDC(vb,  bxy[k], bz[k]);
                LDC(vcc, cxy[k], cz[k]);
                w[k] = (i < K2) ? __float2int_rn(tw[j] * SCALE) : 0;
            }
            #pragma unroll
            for (int d = 0; d < NDIR; ++d) {
                half2v dxy = upk(sdxy[d]), dz = upk(sdz[d]);
                #pragma unroll
                for (int k = 0; k < 2; ++k) {
                    float h = fmaxf(fmaxf(hdot(axy[k], dxy, hdot(az[k], dz, BIAS)),
                                          hdot(bxy[k], dxy, hdot(bz[k], dz, BIAS))),
                                    hdot(cxy[k], dxy, hdot(cz[k], dz, BIAS)));
                    atomicAdd(&hist[d * NH + bin_of(h)], w[k]);
                }
            }
        }

        cur = __shfl(nxt, 0, 64);   // vmcnt wait lands here, after the compute
    }
    #undef LDC

    __syncthreads();
    int* part = (int*)ws + part_off + (blockIdx.x & (P - 1)) * (NDIR * NH);
    for (int i = threadIdx.x; i < NDIR * NH; i += BLK) {
        int v = hist[i];
        if (v != 0) atomicAdd(&part[i], v);
    }
}

// one block per dir: sum P partials (int64-exact), inclusive scan over 256 bins, scale to float
__global__ void wect_reduce_kernel(const float* __restrict__ ws, int P, int part_off,
                                   float* __restrict__ out) {
    __shared__ long long s[NH];
    int d = blockIdx.x, h = threadIdx.x;
    const int* part = (const int*)ws + part_off + d * NH + h;
    long long acc = 0;
    #pragma unroll 4
    for (int p = 0; p < P; ++p)
        acc += (long long)part[p * (NDIR * NH)];
    s[h] = acc;
    __syncthreads();
    #pragma unroll
    for (int off = 1; off < NH; off <<= 1) {
        long long v = (h >= off) ? s[h - off] : 0;
        __syncthreads();
        s[h] += v;
        __syncthreads();
    }
    out[d * NH + h] = (float)((double)s[h] * INVSCALE);
}

extern "C" void kernel_launch(void* const* d_in, const int* in_sizes, int n_in,
                              void* d_out, int out_size, void* d_ws, size_t ws_size,
                              hipStream_t stream) {
    const float* dirs = (const float*)d_in[0];
    const float* vc   = (const float*)d_in[1];
    const float* vw   = (const float*)d_in[2];
    const int*   ev   = (const int*)d_in[3];
    const float* ew   = (const float*)d_in[4];
    const int*   tv   = (const int*)d_in[5];
    const float* tw   = (const float*)d_in[6];
    int K0 = in_sizes[2];
    int K1 = in_sizes[4];
    int K2 = in_sizes[6];

    float* ws  = (float*)d_ws;
    float* out = (float*)d_out;

    long long words = (long long)(ws_size / 4);

    // packed path needs table (2*K0 words) + >=8 partials
    int  part_off = WS_TAB + 2 * K0;
    bool packed   = (words - part_off) >= 8LL * NDIR * NH;
    if (!packed) part_off = WS_TAB;

    long long availP = (words - part_off) / (NDIR * NH);
    int P = 1;
    while (P * 2 <= availP && P < 64) P *= 2;

    // cost-balanced unit schedule (shard boundaries only; balance via stealing)
    int N0 = (K0 + UNIT - 1) / UNIT;
    int N1 = (K1 + UNIT - 1) / UNIT;
    int N2 = (K2 + UNIT - 1) / UNIT;
    long long C0 = (long long)N0 * CV;
    long long C1 = (long long)N1 * CE;
    long long Ctot = C0 + C1 + (long long)N2 * CT;

    if (packed) {
        wect_prep_kernel<true><<<PACKB, 512, 0, stream>>>(
            dirs, vc, K0, N0, N1, C0, C1, Ctot, P, part_off, ws);
        wect_hist_kernel<true><<<NB, BLK, 0, stream>>>(
            vc, vw, ev, ew, tv, tw, K0, K1, K2, N0, N1, N2, C0, C1, Ctot, P, part_off, ws);
    } else {
        wect_prep_kernel<false><<<PACKB, 512, 0, stream>>>(
            dirs, vc, K0, N0, N1, C0, C1, Ctot, P, part_off, ws);
        wect_hist_kernel<false><<<NB, BLK, 0, stream>>>(
            vc, vw, ev, ew, tv, tw, K0, K1, K2, N0, N1, N2, C0, C1, Ctot, P, part_off, ws);
    }
    wect_reduce_kernel<<<NDIR, NH, 0, stream>>>(ws, P, part_off, out);
}

// Round 2
// 69.967 us; speedup vs baseline: 1.6431x; 1.6431x over previous
//
#include <hip/hip_runtime.h>
#include <math.h>

#define NDIR 32
#define NH   256
#define BLK  512    // 8 waves/block
#define NB   1024   // 4 blocks/CU resident (LDS-capped)
#define PACKB 256   // prep grid (one max-slot per block)
#define UNIT 128    // items per work unit (2 x 64 lanes)
#define SCALE    2048.0f
#define INVSCALE (1.0 / 2048.0)
#define BIAS  128.5f   // 127.5 (ref bias) + 1.0 (ceil folded into trunc)

// unit costs (relative VALU weight ~1 : 1.5 : 2)
#define CV 64
#define CE 96
#define CT 128

// ws layout in 4-byte words:
//  [8 .. 104)    : normalized dirs, 32 x 3 floats
//  [128 .. 384)  : per-block max(norm^2) slots (PACKB floats)
//  [512 .. 512+2*K0) : packed f16 vertex table (uint2 per vertex), packed path only
//  [part_off ..)     : P partial int histograms, each 32*256 int32
#define WS_DIRS 8
#define WS_BMAX 128
#define WS_TAB  512

typedef _Float16 half2v __attribute__((ext_vector_type(2)));

__device__ __forceinline__ unsigned rfl_u(unsigned x) { return __builtin_amdgcn_readfirstlane(x); }

__device__ __forceinline__ unsigned pack2(float x, float y) {
    union { half2v h; unsigned u; } c;
    c.h = half2v{(_Float16)x, (_Float16)y};   // RNE (v_cvt_f16_f32)
    return c.u;
}
__device__ __forceinline__ half2v upk(unsigned u) {
    union { unsigned u; half2v h; } c; c.u = u; return c.h;
}
__device__ __forceinline__ float hdot(half2v a, half2v b, float acc) {
#if __has_builtin(__builtin_amdgcn_fdot2)
    return __builtin_amdgcn_fdot2(a, b, acc, false);
#else
    return acc + (float)a.x * (float)b.x + (float)a.y * (float)b.y;
#endif
}
// bin = clip(trunc(hs), 0, 255); hs carries BIAS -> max+min + v_cvt_i32_f32
__device__ __forceinline__ int bin_of(float hs) {
    return (int)fminf(fmaxf(hs, 0.0f), 255.0f);
}

// monotone cost -> unit index (ceil), exact partition across blocks
__device__ __forceinline__ int cost_to_unit(long long cost, int N0, int N1,
                                            long long C0, long long C1) {
    if (cost <= C0) return (int)((cost + (CV - 1)) / CV);
    cost -= C0;
    if (cost <= C1) return N0 + (int)((cost + (CE - 1)) / CE);
    cost -= C1;
    return N0 + N1 + (int)((cost + (CT - 1)) / CT);
}

// prep: zero partials + normalize dirs + pack f16 table + per-block max slot (no atomics)
template <bool PACKED>
__global__ void __launch_bounds__(512) wect_prep_kernel(
    const float* __restrict__ dirs, const float* __restrict__ vc, int K0,
    int P, int part_off, float* __restrict__ ws)
{
    int tid  = blockIdx.x * blockDim.x + threadIdx.x;
    int nthr = gridDim.x * blockDim.x;
    for (int i = tid; i < P * NDIR * NH; i += nthr)
        ((int*)ws)[part_off + i] = 0;
    if (blockIdx.x == 0 && threadIdx.x >= 64 && threadIdx.x < 64 + NDIR) {
        int d = threadIdx.x - 64;
        float x = dirs[d * 3 + 0], y = dirs[d * 3 + 1], z = dirs[d * 3 + 2];
        float n = fmaxf(sqrtf(x * x + y * y + z * z), 1e-12f);
        ws[WS_DIRS + d * 3 + 0] = x / n;
        ws[WS_DIRS + d * 3 + 1] = y / n;
        ws[WS_DIRS + d * 3 + 2] = z / n;
    }
    float m = 0.0f;
    uint2* tab = (uint2*)(ws + WS_TAB);
    for (int i = tid; i < K0; i += nthr) {
        float x = vc[3 * i + 0], y = vc[3 * i + 1], z = vc[3 * i + 2];
        m = fmaxf(m, x * x + y * y + z * z);
        if (PACKED) tab[i] = make_uint2(pack2(x, y), pack2(z, 0.0f));
    }
    __shared__ float wm[8];
    #pragma unroll
    for (int off = 32; off > 0; off >>= 1)
        m = fmaxf(m, __shfl_down(m, off, 64));
    if ((threadIdx.x & 63) == 0) wm[threadIdx.x >> 6] = m;
    __syncthreads();
    if (threadIdx.x == 0) {
        float r = wm[0];
        #pragma unroll
        for (int i = 1; i < 8; ++i) r = fmaxf(r, wm[i]);
        ws[WS_BMAX + blockIdx.x] = r;
    }
}

template <bool PACKED>
__global__ void __launch_bounds__(BLK, 8) wect_hist_kernel(
    const float* __restrict__ vc, const float* __restrict__ vw,
    const int*   __restrict__ ev, const float* __restrict__ ew,
    const int*   __restrict__ tv, const float* __restrict__ tw,
    int K0, int K1, int K2, int N0, int N1, int N2,
    long long C0, long long C1, long long Ctot,
    int P, int part_off, float* __restrict__ ws)
{
    __shared__ int hist[NDIR * NH];   // 32 KB -> 4 blocks/CU (512 thr) = 32 waves/CU
    __shared__ int uctr;              // within-block work-steal cursor (LDS atomic)
    for (int i = threadIdx.x; i < NDIR * NH; i += BLK) hist[i] = 0;

    const int wave = threadIdx.x >> 6;
    const int lane = threadIdx.x & 63;

    // static cost partition at BLOCK granularity (error ~1 unit in ~23: small);
    // within-block wave balance via LDS steal counter (error ~1 unit per wave-slot).
    const int Ub0 = cost_to_unit((long long)blockIdx.x * Ctot / NB, N0, N1, C0, C1);
    const int Ub1 = cost_to_unit((long long)(blockIdx.x + 1) * Ctot / NB, N0, N1, C0, C1);
    if (threadIdx.x == 0) uctr = Ub0 + 8;   // 8 waves seed Ub0..Ub0+7

    // reduce per-block max slots (wave-local, no atomics)
    float m = 0.0f;
    for (int i = lane; i < PACKB; i += 64) m = fmaxf(m, ws[WS_BMAX + i]);
    #pragma unroll
    for (int off = 32; off > 0; off >>= 1)
        m = fmaxf(m, __shfl_xor(m, off, 64));
    float maxh = fmaxf(sqrtf(m), 1e-12f);
    float inv  = 127.5f / maxh;

    // all 32 dirs per wave, packed f16 pairs pinned in SGPRs (64 SGPRs)
    unsigned sdxy[NDIR], sdz[NDIR];
    #pragma unroll
    for (int d = 0; d < NDIR; ++d) {
        float dx = ws[WS_DIRS + 3 * d + 0] * inv;
        float dy = ws[WS_DIRS + 3 * d + 1] * inv;
        float dz = ws[WS_DIRS + 3 * d + 2] * inv;
        sdxy[d] = rfl_u(pack2(dx, dy));
        sdz[d]  = rfl_u(pack2(dz, 0.0f));
    }
    __syncthreads();

    const uint2* tab = (const uint2*)(ws + WS_TAB);
    #define LDC(J, CXY, CZ)                                                  \
        do {                                                                 \
            if constexpr (PACKED) {                                          \
                uint2 r = tab[J];                                            \
                CXY = upk(r.x); CZ = upk(r.y);                               \
            } else {                                                         \
                float _x = vc[3 * (J) + 0], _y = vc[3 * (J) + 1], _z = vc[3 * (J) + 2]; \
                CXY = half2v{(_Float16)_x, (_Float16)_y};                    \
                CZ  = half2v{(_Float16)_z, (_Float16)0.0f};                  \
            }                                                                \
        } while (0)

    // steal loop: grab-next is prefetched (LDS atomic, in-order DS queue ->
    // result ready long before the end-of-unit broadcast needs it)
    int cur = Ub0 + wave;
    while (cur < Ub1) {
        int nxt = 0;
        if (lane == 0) nxt = atomicAdd(&uctr, 1);
        const int u = cur;

        if (u < N0) {
            // ---- vertex unit: sign +1 ----
            int base = u * UNIT;
            half2v xy[2], z[2]; int w[2];
            #pragma unroll
            for (int k = 0; k < 2; ++k) {
                int i = base + k * 64 + lane;
                int j = (i < K0) ? i : 0;
                LDC(j, xy[k], z[k]);
                w[k] = (i < K0) ? __float2int_rn(vw[j] * SCALE) : 0;
            }
            #pragma unroll
            for (int d = 0; d < NDIR; ++d) {
                half2v dxy = upk(sdxy[d]), dz = upk(sdz[d]);
                #pragma unroll
                for (int k = 0; k < 2; ++k) {
                    float h = hdot(xy[k], dxy, hdot(z[k], dz, BIAS));
                    atomicAdd(&hist[d * NH + bin_of(h)], w[k]);
                }
            }
        } else if (u < N0 + N1) {
            // ---- edge unit: sign -1 ----
            int base = (u - N0) * UNIT;
            half2v axy[2], az[2], bxy[2], bz[2]; int w[2];
            #pragma unroll
            for (int k = 0; k < 2; ++k) {
                int i = base + k * 64 + lane;
                int j = (i < K1) ? i : 0;
                int2 e = ((const int2*)ev)[j];
                LDC(e.x, axy[k], az[k]);
                LDC(e.y, bxy[k], bz[k]);
                w[k] = (i < K1) ? -__float2int_rn(ew[j] * SCALE) : 0;
            }
            #pragma unroll
            for (int d = 0; d < NDIR; ++d) {
                half2v dxy = upk(sdxy[d]), dz = upk(sdz[d]);
                #pragma unroll
                for (int k = 0; k < 2; ++k) {
                    float h = fmaxf(hdot(axy[k], dxy, hdot(az[k], dz, BIAS)),
                                    hdot(bxy[k], dxy, hdot(bz[k], dz, BIAS)));
                    atomicAdd(&hist[d * NH + bin_of(h)], w[k]);
                }
            }
        } else {
            // ---- triangle unit: sign +1 ----
            int base = (u - N0 - N1) * UNIT;
            half2v axy[2], az[2], bxy[2], bz[2], cxy[2], cz[2]; int w[2];
            #pragma unroll
            for (int k = 0; k < 2; ++k) {
                int i = base + k * 64 + lane;
                int j = (i < K2) ? i : 0;
                int va = tv[3 * j + 0], vb = tv[3 * j + 1], vcc = tv[3 * j + 2];
                LDC(va,  axy[k], az[k]);
                LDC(vb,  bxy[k], bz[k]);
                LDC(vcc, cxy[k], cz[k]);
                w[k] = (i < K2) ? __float2int_rn(tw[j] * SCALE) : 0;
            }
            #pragma unroll
            for (int d = 0; d < NDIR; ++d) {
                half2v dxy = upk(sdxy[d]), dz = upk(sdz[d]);
                #pragma unroll
                for (int k = 0; k < 2; ++k) {
                    float h = fmaxf(fmaxf(hdot(axy[k], dxy, hdot(az[k], dz, BIAS)),
                                          hdot(bxy[k], dxy, hdot(bz[k], dz, BIAS))),
                                    hdot(cxy[k], dxy, hdot(cz[k], dz, BIAS)));
                    atomicAdd(&hist[d * NH + bin_of(h)], w[k]);
                }
            }
        }

        cur = __shfl(nxt, 0, 64);   // lane0's grabbed unit, broadcast at unit end
    }
    #undef LDC

    __syncthreads();
    int* part = (int*)ws + part_off + (blockIdx.x & (P - 1)) * (NDIR * NH);
    for (int i = threadIdx.x; i < NDIR * NH; i += BLK) {
        int v = hist[i];
        if (v != 0) atomicAdd(&part[i], v);
    }
}

// one block per dir: sum P partials (int64-exact), inclusive scan over 256 bins, scale to float
__global__ void wect_reduce_kernel(const float* __restrict__ ws, int P, int part_off,
                                   float* __restrict__ out) {
    __shared__ long long s[NH];
    int d = blockIdx.x, h = threadIdx.x;
    const int* part = (const int*)ws + part_off + d * NH + h;
    long long acc = 0;
    #pragma unroll 4
    for (int p = 0; p < P; ++p)
        acc += (long long)part[p * (NDIR * NH)];
    s[h] = acc;
    __syncthreads();
    #pragma unroll
    for (int off = 1; off < NH; off <<= 1) {
        long long v = (h >= off) ? s[h - off] : 0;
        __syncthreads();
        s[h] += v;
        __syncthreads();
    }
    out[d * NH + h] = (float)((double)s[h] * INVSCALE);
}

extern "C" void kernel_launch(void* const* d_in, const int* in_sizes, int n_in,
                              void* d_out, int out_size, void* d_ws, size_t ws_size,
                              hipStream_t stream) {
    const float* dirs = (const float*)d_in[0];
    const float* vc   = (const float*)d_in[1];
    const float* vw   = (const float*)d_in[2];
    const int*   ev   = (const int*)d_in[3];
    const float* ew   = (const float*)d_in[4];
    const int*   tv   = (const int*)d_in[5];
    const float* tw   = (const float*)d_in[6];
    int K0 = in_sizes[2];
    int K1 = in_sizes[4];
    int K2 = in_sizes[6];

    float* ws  = (float*)d_ws;
    float* out = (float*)d_out;

    long long words = (long long)(ws_size / 4);

    // packed path needs table (2*K0 words) + >=8 partials
    int  part_off = WS_TAB + 2 * K0;
    bool packed   = (words - part_off) >= 8LL * NDIR * NH;
    if (!packed) part_off = WS_TAB;

    long long availP = (words - part_off) / (NDIR * NH);
    int P = 1;
    while (P * 2 <= availP && P < 64) P *= 2;

    // cost-balanced unit schedule (block boundaries static; wave balance via LDS steal)
    int N0 = (K0 + UNIT - 1) / UNIT;
    int N1 = (K1 + UNIT - 1) / UNIT;
    int N2 = (K2 + UNIT - 1) / UNIT;
    long long C0 = (long long)N0 * CV;
    long long C1 = (long long)N1 * CE;
    long long Ctot = C0 + C1 + (long long)N2 * CT;

    if (packed) {
        wect_prep_kernel<true><<<PACKB, 512, 0, stream>>>(dirs, vc, K0, P, part_off, ws);
        wect_hist_kernel<true><<<NB, BLK, 0, stream>>>(
            vc, vw, ev, ew, tv, tw, K0, K1, K2, N0, N1, N2, C0, C1, Ctot, P, part_off, ws);
    } else {
        wect_prep_kernel<false><<<PACKB, 512, 0, stream>>>(dirs, vc, K0, P, part_off, ws);
        wect_hist_kernel<false><<<NB, BLK, 0, stream>>>(
            vc, vw, ev, ew, tv, tw, K0, K1, K2, N0, N1, N2, C0, C1, Ctot, P, part_off, ws);
    }
    wect_reduce_kernel<<<NDIR, NH, 0, stream>>>(ws, P, part_off, out);
}

// Round 3
// 62.098 us; speedup vs baseline: 1.8513x; 1.1267x over previous
//
#include <hip/hip_runtime.h>
#include <math.h>

#define NDIR 32
#define NH   256
#define BLK  512    // 8 waves/block
#define NB   1024   // 4 blocks/CU resident (LDS-capped), grid == capacity
#define PACKB 256   // prep grid (one max-slot per block)
#define UNIT 64     // items per work unit (1 x 64 lanes) -> fine steal granularity
#define SCALE    2048.0f
#define INVSCALE (1.0 / 2048.0)
#define BIAS  128.5f   // 127.5 (ref bias) + 1.0 (ceil folded into trunc)

// ws layout in 4-byte words:
//  [8 .. 104)    : normalized dirs, 32 x 3 floats
//  [128 .. 384)  : per-block max(norm^2) slots (PACKB floats)
//  [512 .. 512+2*K0) : packed f16 vertex table (uint2 per vertex), packed path only
//  [part_off ..)     : P partial int histograms, each 32*256 int32
#define WS_DIRS 8
#define WS_BMAX 128
#define WS_TAB  512

typedef _Float16 half2v __attribute__((ext_vector_type(2)));

__device__ __forceinline__ unsigned rfl_u(unsigned x) { return __builtin_amdgcn_readfirstlane(x); }

__device__ __forceinline__ unsigned pack2(float x, float y) {
    union { half2v h; unsigned u; } c;
    c.h = half2v{(_Float16)x, (_Float16)y};   // RNE (v_cvt_f16_f32)
    return c.u;
}
__device__ __forceinline__ half2v upk(unsigned u) {
    union { unsigned u; half2v h; } c; c.u = u; return c.h;
}
__device__ __forceinline__ float hdot(half2v a, half2v b, float acc) {
#if __has_builtin(__builtin_amdgcn_fdot2)
    return __builtin_amdgcn_fdot2(a, b, acc, false);
#else
    return acc + (float)a.x * (float)b.x + (float)a.y * (float)b.y;
#endif
}
// bin = clip(trunc(hs), 0, 255); hs carries BIAS -> max+min + v_cvt_i32_f32
__device__ __forceinline__ int bin_of(float hs) {
    return (int)fminf(fmaxf(hs, 0.0f), 255.0f);
}

// prep: zero partials + normalize dirs + pack f16 table + per-block max slot (no atomics)
template <bool PACKED>
__global__ void __launch_bounds__(512) wect_prep_kernel(
    const float* __restrict__ dirs, const float* __restrict__ vc, int K0,
    int P, int part_off, float* __restrict__ ws)
{
    int tid  = blockIdx.x * blockDim.x + threadIdx.x;
    int nthr = gridDim.x * blockDim.x;
    for (int i = tid; i < P * NDIR * NH; i += nthr)
        ((int*)ws)[part_off + i] = 0;
    if (blockIdx.x == 0 && threadIdx.x >= 64 && threadIdx.x < 64 + NDIR) {
        int d = threadIdx.x - 64;
        float x = dirs[d * 3 + 0], y = dirs[d * 3 + 1], z = dirs[d * 3 + 2];
        float n = fmaxf(sqrtf(x * x + y * y + z * z), 1e-12f);
        ws[WS_DIRS + d * 3 + 0] = x / n;
        ws[WS_DIRS + d * 3 + 1] = y / n;
        ws[WS_DIRS + d * 3 + 2] = z / n;
    }
    float m = 0.0f;
    uint2* tab = (uint2*)(ws + WS_TAB);
    for (int i = tid; i < K0; i += nthr) {
        float x = vc[3 * i + 0], y = vc[3 * i + 1], z = vc[3 * i + 2];
        m = fmaxf(m, x * x + y * y + z * z);
        if (PACKED) tab[i] = make_uint2(pack2(x, y), pack2(z, 0.0f));
    }
    __shared__ float wm[8];
    #pragma unroll
    for (int off = 32; off > 0; off >>= 1)
        m = fmaxf(m, __shfl_down(m, off, 64));
    if ((threadIdx.x & 63) == 0) wm[threadIdx.x >> 6] = m;
    __syncthreads();
    if (threadIdx.x == 0) {
        float r = wm[0];
        #pragma unroll
        for (int i = 1; i < 8; ++i) r = fmaxf(r, wm[i]);
        ws[WS_BMAX + blockIdx.x] = r;
    }
}

// Unified unit space [0, Ntot): [0,N0) vertex, [N0,N01) edge, [N01,Ntot) tri.
// Block b owns the TYPE-STRIPED set {b, b+NB, b+2NB, ...}: every block gets the
// same type mix (+-1 unit) -> identical block cost with NO cost model.
// Within block, waves balance via LDS steal counter over the local index n.
template <bool PACKED>
__global__ void __launch_bounds__(BLK, 8) wect_hist_kernel(
    const float* __restrict__ vc, const float* __restrict__ vw,
    const int*   __restrict__ ev, const float* __restrict__ ew,
    const int*   __restrict__ tv, const float* __restrict__ tw,
    int K0, int K1, int K2, int N0, int N01, int Ntot,
    int P, int part_off, float* __restrict__ ws)
{
    __shared__ int hist[NDIR * NH];   // 32 KB -> 4 blocks/CU (512 thr) = 32 waves/CU
    __shared__ int nctr;              // within-block work-steal cursor (LDS atomic)
    for (int i = threadIdx.x; i < (NDIR * NH) / 4; i += BLK)
        ((int4*)hist)[i] = make_int4(0, 0, 0, 0);

    const int wave = threadIdx.x >> 6;
    const int lane = threadIdx.x & 63;
    const int b    = blockIdx.x;
    const int nu   = (Ntot - b + NB - 1) / NB;   // units in this block's stripe
    if (threadIdx.x == 0) nctr = 8;              // 8 waves seed n = 0..7

    // reduce per-block max slots (wave-local, no atomics)
    float m = 0.0f;
    for (int i = lane; i < PACKB; i += 64) m = fmaxf(m, ws[WS_BMAX + i]);
    #pragma unroll
    for (int off = 32; off > 0; off >>= 1)
        m = fmaxf(m, __shfl_xor(m, off, 64));
    float maxh = fmaxf(sqrtf(m), 1e-12f);
    float inv  = 127.5f / maxh;

    // all 32 dirs per wave, packed f16 pairs pinned in SGPRs (64 SGPRs)
    unsigned sdxy[NDIR], sdz[NDIR];
    #pragma unroll
    for (int d = 0; d < NDIR; ++d) {
        float dx = ws[WS_DIRS + 3 * d + 0] * inv;
        float dy = ws[WS_DIRS + 3 * d + 1] * inv;
        float dz = ws[WS_DIRS + 3 * d + 2] * inv;
        sdxy[d] = rfl_u(pack2(dx, dy));
        sdz[d]  = rfl_u(pack2(dz, 0.0f));
    }
    __syncthreads();

    const uint2* tab = (const uint2*)(ws + WS_TAB);
    #define LDC(J, CXY, CZ)                                                  \
        do {                                                                 \
            if constexpr (PACKED) {                                          \
                uint2 r = tab[J];                                            \
                CXY = upk(r.x); CZ = upk(r.y);                               \
            } else {                                                         \
                float _x = vc[3 * (J) + 0], _y = vc[3 * (J) + 1], _z = vc[3 * (J) + 2]; \
                CXY = half2v{(_Float16)_x, (_Float16)_y};                    \
                CZ  = half2v{(_Float16)_z, (_Float16)0.0f};                  \
            }                                                                \
        } while (0)

    // steal loop: grab-next is prefetched (LDS atomic, latency hidden under unit)
    int n = wave;
    while (n < nu) {
        int nxt = 0;
        if (lane == 0) nxt = atomicAdd(&nctr, 1);
        const int u = b + n * NB;

        if (u < N0) {
            // ---- vertex unit: sign +1 ----
            int i = u * UNIT + lane;
            int j = (i < K0) ? i : 0;
            half2v xy, z;
            LDC(j, xy, z);
            int w = (i < K0) ? __float2int_rn(vw[j] * SCALE) : 0;
            #pragma unroll
            for (int d = 0; d < NDIR; ++d) {
                half2v dxy = upk(sdxy[d]), dz = upk(sdz[d]);
                float h = hdot(xy, dxy, hdot(z, dz, BIAS));
                atomicAdd(&hist[d * NH + bin_of(h)], w);
            }
        } else if (u < N01) {
            // ---- edge unit: sign -1 ----
            int i = (u - N0) * UNIT + lane;
            int j = (i < K1) ? i : 0;
            int2 e = ((const int2*)ev)[j];
            half2v axy, az, bxy, bz;
            LDC(e.x, axy, az);
            LDC(e.y, bxy, bz);
            int w = (i < K1) ? -__float2int_rn(ew[j] * SCALE) : 0;
            #pragma unroll
            for (int d = 0; d < NDIR; ++d) {
                half2v dxy = upk(sdxy[d]), dz = upk(sdz[d]);
                float h = fmaxf(hdot(axy, dxy, hdot(az, dz, BIAS)),
                                hdot(bxy, dxy, hdot(bz, dz, BIAS)));
                atomicAdd(&hist[d * NH + bin_of(h)], w);
            }
        } else {
            // ---- triangle unit: sign +1 ----
            int i = (u - N01) * UNIT + lane;
            int j = (i < K2) ? i : 0;
            int va = tv[3 * j + 0], vb = tv[3 * j + 1], vcc = tv[3 * j + 2];
            half2v axy, az, bxy, bz, cxy, cz;
            LDC(va,  axy, az);
            LDC(vb,  bxy, bz);
            LDC(vcc, cxy, cz);
            int w = (i < K2) ? __float2int_rn(tw[j] * SCALE) : 0;
            #pragma unroll
            for (int d = 0; d < NDIR; ++d) {
                half2v dxy = upk(sdxy[d]), dz = upk(sdz[d]);
                float h = fmaxf(fmaxf(hdot(axy, dxy, hdot(az, dz, BIAS)),
                                      hdot(bxy, dxy, hdot(bz, dz, BIAS))),
                                hdot(cxy, dxy, hdot(cz, dz, BIAS)));
                atomicAdd(&hist[d * NH + bin_of(h)], w);
            }
        }

        n = __shfl(nxt, 0, 64);   // lane0's grabbed local index, broadcast at unit end
    }
    #undef LDC

    __syncthreads();
    int* part = (int*)ws + part_off + (blockIdx.x & (P - 1)) * (NDIR * NH);
    for (int i = threadIdx.x; i < NDIR * NH; i += BLK) {
        int v = hist[i];
        if (v != 0) atomicAdd(&part[i], v);
    }
}

// one block per dir: sum P partials (int64-exact), inclusive scan over 256 bins, scale to float
__global__ void wect_reduce_kernel(const float* __restrict__ ws, int P, int part_off,
                                   float* __restrict__ out) {
    __shared__ long long s[NH];
    int d = blockIdx.x, h = threadIdx.x;
    const int* part = (const int*)ws + part_off + d * NH + h;
    long long acc = 0;
    #pragma unroll 4
    for (int p = 0; p < P; ++p)
        acc += (long long)part[p * (NDIR * NH)];
    s[h] = acc;
    __syncthreads();
    #pragma unroll
    for (int off = 1; off < NH; off <<= 1) {
        long long v = (h >= off) ? s[h - off] : 0;
        __syncthreads();
        s[h] += v;
        __syncthreads();
    }
    out[d * NH + h] = (float)((double)s[h] * INVSCALE);
}

extern "C" void kernel_launch(void* const* d_in, const int* in_sizes, int n_in,
                              void* d_out, int out_size, void* d_ws, size_t ws_size,
                              hipStream_t stream) {
    const float* dirs = (const float*)d_in[0];
    const float* vc   = (const float*)d_in[1];
    const float* vw   = (const float*)d_in[2];
    const int*   ev   = (const int*)d_in[3];
    const float* ew   = (const float*)d_in[4];
    const int*   tv   = (const int*)d_in[5];
    const float* tw   = (const float*)d_in[6];
    int K0 = in_sizes[2];
    int K1 = in_sizes[4];
    int K2 = in_sizes[6];

    float* ws  = (float*)d_ws;
    float* out = (float*)d_out;

    long long words = (long long)(ws_size / 4);

    // packed path needs table (2*K0 words) + >=8 partials
    int  part_off = WS_TAB + 2 * K0;
    bool packed   = (words - part_off) >= 8LL * NDIR * NH;
    if (!packed) part_off = WS_TAB;

    long long availP = (words - part_off) / (NDIR * NH);
    int P = 1;
    while (P * 2 <= availP && P < 16) P *= 2;   // 16 partials: enough sharding,
                                                // 4x less zero+reduce traffic

    // unified, type-striped unit space (no cost model)
    int N0 = (K0 + UNIT - 1) / UNIT;
    int N1 = (K1 + UNIT - 1) / UNIT;
    int N2 = (K2 + UNIT - 1) / UNIT;
    int N01 = N0 + N1;
    int Ntot = N01 + N2;

    if (packed) {
        wect_prep_kernel<true><<<PACKB, 512, 0, stream>>>(dirs, vc, K0, P, part_off, ws);
        wect_hist_kernel<true><<<NB, BLK, 0, stream>>>(
            vc, vw, ev, ew, tv, tw, K0, K1, K2, N0, N01, Ntot, P, part_off, ws);
    } else {
        wect_prep_kernel<false><<<PACKB, 512, 0, stream>>>(dirs, vc, K0, P, part_off, ws);
        wect_hist_kernel<false><<<NB, BLK, 0, stream>>>(
            vc, vw, ev, ew, tv, tw, K0, K1, K2, N0, N01, Ntot, P, part_off, ws);
    }
    wect_reduce_kernel<<<NDIR, NH, 0, stream>>>(ws, P, part_off, out);
}